// Round 17
// baseline (253.896 us; speedup 1.0000x reference)
//
#include <hip/hip_runtime.h>
#include <stdint.h>

#define B_ 4
#define T_ 2048
#define C_ 1024
#define H_ 16
#define HD_ 64

typedef __attribute__((ext_vector_type(8))) short short8;
typedef __attribute__((ext_vector_type(4))) float f32x4;

typedef uint32_t __attribute__((address_space(3))) lds_u32;
typedef const uint32_t __attribute__((address_space(1))) glb_u32;

__device__ inline void async16(const void* g, void* l) {
    __builtin_amdgcn_global_load_lds((glb_u32*)g, (lds_u32*)l, 16, 0, 0);
}

__device__ inline short f2bf(float f) {
    union { float f; uint32_t u; } x; x.f = f;
    uint32_t r = (x.u + 0x7fffu + ((x.u >> 16) & 1u)) >> 16;
    return (short)r;
}
__device__ inline float bf2f(short b) {
    union { uint32_t u; float f; } x; x.u = ((uint32_t)(uint16_t)b) << 16;
    return x.f;
}
// v_cvt_pk_bf16_f32: packs two f32 into one u32 of 2x bf16 (RNE). No builtin
// on gfx950 (guide T12 / m240) -> inline asm.
__device__ inline uint32_t cvt_pk_bf16(float lo, float hi) {
    uint32_t r;
    asm("v_cvt_pk_bf16_f32 %0, %1, %2" : "=v"(r) : "v"(lo), "v"(hi));
    return r;
}

#define FENCE asm volatile("" ::: "memory")
#define BAR   do { FENCE; __builtin_amdgcn_s_barrier(); FENCE; } while (0)
#define VMC6  asm volatile("s_waitcnt vmcnt(6)" ::: "memory")

// Dtype detect + canonicalize (r12/r13-proven). r15: only launched when the
// HOST cannot prove bf16 from in_sizes (f32 or ambiguous); bf16-proven runs
// skip this kernel entirely. bf16 device path: flag only, no copies.
__global__ void convert_all(const void* __restrict__ x,  const void* __restrict__ wq,
                            const void* __restrict__ wp, const void* __restrict__ bias,
                            short* __restrict__ xd, short* __restrict__ wqd,
                            short* __restrict__ wpd, short* __restrict__ biasd,
                            int* __restrict__ flag_out)
{
    __shared__ int cnt;
    if (threadIdx.x == 0) cnt = 0;
    __syncthreads();
    int sane = 0;
    const uint32_t* xu = (const uint32_t*)x;
    for (int i = threadIdx.x; i < 1024; i += 256) {
        float v = bf2f((short)(xu[i] & 0xFFFFu));
        float a = fabsf(v);
        if (a > 1e-5f && a < 1e5f) sane++;
    }
    atomicAdd(&cnt, sane);
    __syncthreads();
    const int isf32 = (cnt < 512) ? 1 : 0;

    const int blk = blockIdx.x;
    if (blk == 6144 && threadIdx.x == 0) *flag_out = isf32;
    if (!isf32) return;                      // bf16 inputs: no copies needed

    const void* src; short* dst; int base, n;
    if (blk < 4096)      { src = x;    dst = xd;    base = blk;        n = B_*T_*C_; }
    else if (blk < 5632) { src = wq;   dst = wqd;   base = blk - 4096; n = 3*C_*C_; }
    else if (blk < 6144) { src = wp;   dst = wpd;   base = blk - 5632; n = C_*C_; }
    else                 { src = bias; dst = biasd; base = 0;          n = C_; }
    const int i = (base * 256 + threadIdx.x) * 8;
    if (i >= n) return;
    const float* s = (const float*)src;
    short8 o;
#pragma unroll
    for (int j = 0; j < 8; j++) o[j] = f2bf(s[i + j]);
    *(short8*)&dst[i] = o;
}

// ---------------------------------------------------------------------------
// GEMM v3 (r7/r13 proven): BM=128 x BN=256, BK=64, 8 waves, TRIPLE-buffered
// LDS (144 KB), ONE barrier + ONE counted vmcnt(6) per K-tile. 0 bank
// conflicts, exact grids (768, 256), no epilogue RMW.
// r15: isf32 passed BY VALUE when host-known (isf32_arg in {0,1}); -1 falls
// back to the device flag read (r13-proven path).
// r14 ERRATUM stands: B must stay LDS-staged (direct global B-fragments have
// 2KB lane stride = 16x request amplification; regressed 2.3x).
// ---------------------------------------------------------------------------
template <bool DUAL>
__global__ __launch_bounds__(512, 2) void gemm8(
    const short* __restrict__ Abf,  const short* __restrict__ Araw,
    const short* __restrict__ Bbf,  const short* __restrict__ Braw,
    const short* __restrict__ biasbf, const short* __restrict__ biasraw,
    void* __restrict__ Cout, int M, int N, int K,
    int isf32_arg, const int* __restrict__ flag)
{
    __shared__ short lds[73728];         // 144 KB: A [3][128][64] | B [3][256][64]
    const int isf32 = (isf32_arg >= 0) ? isf32_arg : *flag;
    const short* __restrict__ A  = isf32 ? Abf : Araw;
    const short* __restrict__ Bm = isf32 ? Bbf : Braw;
    const short* bias_bf = DUAL ? (isf32 ? biasbf : biasraw) : (const short*)0;

    const int tid  = threadIdx.x;
    const int lane = tid & 63;
    const int wid  = tid >> 6;
    const int quad = lane >> 4;
    const int lcol = lane & 15;
    const int wm   = wid >> 2;           // 0..1  (64-row slice)
    const int wn   = wid & 3;            // 0..3  (64-col slice)
    const int nbx  = N >> 8;             // N/256

    // XCD swizzle (grid % 8 == 0 for both gemms)
    const int cpx = gridDim.x >> 3;
    const int wg  = (blockIdx.x & 7) * cpx + (blockIdx.x >> 3);
    const int m0 = (wg / nbx) << 7;
    const int n0 = (wg % nbx) << 8;

    // staging: one async16/thread covers 64 rows x 64 cols (8 KB).
    const int srow = tid >> 3;
    const int sch  = ((tid & 7) ^ (srow & 7)) << 3;
    auto stA = [&](int buf, int i, int kt) {   // i in 0..1
        async16(&A[(size_t)(m0 + i * 64 + srow) * K + kt * 64 + sch],
                &lds[buf * 8192 + i * 4096 + tid * 8]);
    };
    auto stB = [&](int buf, int i, int kt) {   // i in 0..3
        async16(&Bm[(size_t)(n0 + i * 64 + srow) * K + kt * 64 + sch],
                &lds[24576 + buf * 16384 + i * 4096 + tid * 8]);
    };
    auto stage6 = [&](int buf, int kt) {
        stB(buf, 0, kt); stB(buf, 1, kt); stB(buf, 2, kt); stB(buf, 3, kt);
        stA(buf, 0, kt); stA(buf, 1, kt);
    };

    f32x4 acc[4][4];
#pragma unroll
    for (int i = 0; i < 4; i++)
#pragma unroll
        for (int j = 0; j < 4; j++) acc[i][j] = f32x4{0.f, 0.f, 0.f, 0.f};

    short8 a[4][2], b[4][2];
    auto rdA2 = [&](int mb, int buf) {
#pragma unroll
        for (int m2 = 0; m2 < 2; m2++)
#pragma unroll
            for (int ks = 0; ks < 2; ks++)
                a[mb + m2][ks] = *(const short8*)&lds[buf * 8192
                    + (wm * 64 + (mb + m2) * 16 + lcol) * 64
                    + ((((ks << 2) | quad) ^ (lcol & 7)) << 3)];
    };
    auto rdB2 = [&](int nb, int buf) {
#pragma unroll
        for (int n2 = 0; n2 < 2; n2++)
#pragma unroll
            for (int ks = 0; ks < 2; ks++)
                b[nb + n2][ks] = *(const short8*)&lds[24576 + buf * 16384
                    + (wn * 64 + (nb + n2) * 16 + lcol) * 64
                    + ((((ks << 2) | quad) ^ (lcol & 7)) << 3)];
    };
    auto mmq = [&](int mb, int nb) {           // one quadrant: 8 MFMA
#pragma unroll
        for (int m2 = 0; m2 < 2; m2++)
#pragma unroll
            for (int n2 = 0; n2 < 2; n2++)
#pragma unroll
                for (int ks = 0; ks < 2; ks++)
                    acc[mb + m2][nb + n2] = __builtin_amdgcn_mfma_f32_16x16x32_bf16(
                        a[mb + m2][ks], b[nb + n2][ks], acc[mb + m2][nb + n2], 0, 0, 0);
    };

    const int NT = K >> 6;                     // 16 K-tiles
    // prologue: tile0 -> buf0, tile1 -> buf1 (12 calls in flight)
    stage6(0, 0);
    stage6(1, 1);

    int bt = 0, b1i = 1, b2i = 2;
    for (int t = 0; t < NT; ++t) {
        const int ts = (t + 2 < NT) ? t + 2 : NT - 1;  // tail stages go to a
        VMC6;                                          // dead buffer (uniform
        BAR;                                           // vmcnt ledger)
        rdA2(0, bt); rdA2(2, bt); rdB2(0, bt); rdB2(2, bt);
        stage6(b2i, ts);
        __builtin_amdgcn_s_setprio(1);
        mmq(0, 0); mmq(2, 0); mmq(0, 2); mmq(2, 2);
        __builtin_amdgcn_s_setprio(0);
        const int nb = bt;                             // rotate buffers
        bt = b1i; b1i = b2i; b2i = nb;
    }

    // epilogue: row-contiguous store order (nf inner) -> per wave per row
    // 128 B written back-to-back; no partial-line RMW.
    float bv[4];
#pragma unroll
    for (int nf = 0; nf < 4; nf++)
        bv[nf] = bias_bf ? bf2f(bias_bf[n0 + wn * 64 + nf * 16 + lcol]) : 0.f;
#pragma unroll
    for (int mf = 0; mf < 4; mf++)
#pragma unroll
        for (int r = 0; r < 4; r++) {
            const int row = m0 + wm * 64 + mf * 16 + quad * 4 + r;
#pragma unroll
            for (int nf = 0; nf < 4; nf++) {
                const int col = n0 + wn * 64 + nf * 16 + lcol;
                const float val = acc[mf][nf][r] + bv[nf];
                const size_t off = (size_t)row * N + col;
                if (DUAL && isf32) ((float*)Cout)[off] = val;
                else               ((short*)Cout)[off] = f2bf(val);
            }
        }
}

// Flash attention v12 VERBATIM (r7/r12/r13/r15 proven, ~64-66 us): two
// causal-complementary 128-row chunks/block (uniform 34 tiles), in-register
// softmax via swapped QK^T + permuted V staging + cvt_pk pack + mask-hoist +
// ones-MFMA l-sum. Sync topology and m-tile structure FROZEN (r8/r9/r11
// restructures all failed verification).
__global__ __launch_bounds__(256) void attn(const short* __restrict__ qkv,
                                            short* __restrict__ att)
{
    __shared__ short lds_k[64][72];      // K  [key][d], pad 64->72 (stride 36 dw)
    __shared__ short lds_vt[64][68];     // V^T [d][key-slot], pad 64->68

    const int tid  = threadIdx.x;
    const int lane = tid & 63;
    const int wave = tid >> 6;
    const int quad = lane >> 4;
    const int lcol = lane & 15;

    const int bh   = blockIdx.x & 63;    // low bits -> XCD pinned per head
    const int j    = blockIdx.x >> 6;    // pair index 0..7
    const int b    = bh >> 4;            // H = 16
    const int h    = bh & 15;

    const size_t rowstride = 3 * C_;     // 3072
    const size_t bhbase = (size_t)b * T_ * rowstride + (size_t)h * (3 * HD_);

    const int kkey = tid >> 2;           // 0..63
    const int kdp  = (tid & 3) * 16;     // 0,16,32,48
    const int vkey = tid & 63;
    const int vkp  = (vkey & 0x23) | ((vkey & 0x0C) << 1) | ((vkey & 0x10) >> 2);
    const int vd0  = (tid >> 6) * 16;    // 0,16,32,48

    short8 vones;
#pragma unroll
    for (int i = 0; i < 8; i++) vones[i] = (short)0x3F80;

    const short* kp; const short* vp;
    short8 kA, kB, vA, vB;
    const size_t TILE_STEP = (size_t)64 * rowstride;
    auto load_init = [&]() {
        kp = &qkv[bhbase + (size_t)kkey * rowstride + HD_ + kdp];
        vp = &qkv[bhbase + (size_t)vkey * rowstride + 2 * HD_ + vd0];
    };
    auto load_tile = [&]() {
        kA = *(const short8*)kp;
        kB = *(const short8*)(kp + 8);
        vA = *(const short8*)vp;
        vB = *(const short8*)(vp + 8);
        kp += TILE_STEP; vp += TILE_STEP;
    };

    const float SC = 0.1803368801f;      // 0.125 * log2(e), folded into Q
    auto scale_frag = [&](short8 q) {
        short8 r;
#pragma unroll
        for (int i = 0; i < 8; i++) r[i] = f2bf(bf2f(q[i]) * SC);
        return r;
    };

    auto process_chunk = [&](int qblk, bool sync_first) {
        const int q0 = qblk * 128;
        const int qA = q0 + wave * 16;          // m-tile A rows
        const int qB = q0 + 64 + wave * 16;     // m-tile B rows

        short8 qfA0, qfA1, qfB0, qfB1;
        {
            const size_t ba = bhbase + (size_t)(qA + lcol) * rowstride + quad * 8;
            qfA0 = scale_frag(*(const short8*)&qkv[ba]);
            qfA1 = scale_frag(*(const short8*)&qkv[ba + 32]);
            const size_t bb = bhbase + (size_t)(qB + lcol) * rowstride + quad * 8;
            qfB0 = scale_frag(*(const short8*)&qkv[bb]);
            qfB1 = scale_frag(*(const short8*)&qkv[bb + 32]);
        }

        f32x4 oA[4], oB[4], oLA, oLB;
#pragma unroll
        for (int i = 0; i < 4; i++) { oA[i] = f32x4{0.f,0.f,0.f,0.f}; oB[i] = f32x4{0.f,0.f,0.f,0.f}; }
        oLA = f32x4{0.f,0.f,0.f,0.f}; oLB = f32x4{0.f,0.f,0.f,0.f};

        load_init();
        load_tile();

        const int LT = 2 * qblk + 1;            // last tile index
        for (int kt = 0; kt <= LT; ++kt) {
            if (kt || sync_first) __syncthreads();  // prior LDS reads done
            *(short8*)&lds_k[kkey][kdp]     = kA;
            *(short8*)&lds_k[kkey][kdp + 8] = kB;
#pragma unroll
            for (int jj = 0; jj < 8; jj++) {
                lds_vt[vd0 + jj][vkp]     = vA[jj];
                lds_vt[vd0 + 8 + jj][vkp] = vB[jj];
            }
            __syncthreads();
            if (kt < LT) load_tile();            // prefetch overlaps compute

            const int k0 = kt * 64;
            const bool doA = (kt < LT);      // A's range is tiles 0..LT-1

            f32x4 SA[4], SB[4];
#pragma unroll
            for (int t = 0; t < 4; t++) {
                const short8 kf0 = *(const short8*)&lds_k[t * 16 + lcol][quad * 8];
                const short8 kf1 = *(const short8*)&lds_k[t * 16 + lcol][32 + quad * 8];
                SB[t] = f32x4{0.f, 0.f, 0.f, 0.f};
                SB[t] = __builtin_amdgcn_mfma_f32_16x16x32_bf16(kf0, qfB0, SB[t], 0, 0, 0);
                SB[t] = __builtin_amdgcn_mfma_f32_16x16x32_bf16(kf1, qfB1, SB[t], 0, 0, 0);
                if (doA) {
                    SA[t] = f32x4{0.f, 0.f, 0.f, 0.f};
                    SA[t] = __builtin_amdgcn_mfma_f32_16x16x32_bf16(kf0, qfA0, SA[t], 0, 0, 0);
                    SA[t] = __builtin_amdgcn_mfma_f32_16x16x32_bf16(kf1, qfA1, SA[t], 0, 0, 0);
                }
            }

            short8 vf[4][2];
#pragma unroll
            for (int dt = 0; dt < 4; dt++) {
                vf[dt][0] = *(const short8*)&lds_vt[dt * 16 + lcol][quad * 8];
                vf[dt][1] = *(const short8*)&lds_vt[dt * 16 + lcol][32 + quad * 8];
            }

            auto do_mtile = [&](f32x4 (&S)[4], f32x4 (&o)[4], f32x4& oL,
                                int qX, bool maskT) {
                if (maskT) {
                    const int qthr = qX + lcol - k0 - quad * 4;  // per-lane
#pragma unroll
                    for (int t = 0; t < 4; t++)
#pragma unroll
                        for (int r = 0; r < 4; r++) {
                            float e = __builtin_amdgcn_exp2f(S[t][r]);
                            if (t * 16 + r > qthr) e = 0.f;
                            S[t][r] = e;
                        }
                } else {
#pragma unroll
                    for (int t = 0; t < 4; t++)
#pragma unroll
                        for (int r = 0; r < 4; r++)
                            S[t][r] = __builtin_amdgcn_exp2f(S[t][r]);
                }
                union { uint32_t u[4]; short8 s; } p0, p1;
#pragma unroll
                for (int w = 0; w < 4; w++) {
                    const int t0 = w >> 1, r0 = (w & 1) * 2;
                    p0.u[w] = cvt_pk_bf16(S[t0][r0],     S[t0][r0 + 1]);
                    p1.u[w] = cvt_pk_bf16(S[2 + t0][r0], S[2 + t0][r0 + 1]);
                }
                oL = __builtin_amdgcn_mfma_f32_16x16x32_bf16(p0.s, vones, oL, 0, 0, 0);
                oL = __builtin_amdgcn_mfma_f32_16x16x32_bf16(p1.s, vones, oL, 0, 0, 0);
#pragma unroll
                for (int dt = 0; dt < 4; dt++) {
                    o[dt] = __builtin_amdgcn_mfma_f32_16x16x32_bf16(p0.s, vf[dt][0], o[dt], 0, 0, 0);
                    o[dt] = __builtin_amdgcn_mfma_f32_16x16x32_bf16(p1.s, vf[dt][1], o[dt], 0, 0, 0);
                }
            };

            if (doA) do_mtile(SA, oA, oLA, qA, kt == LT - 1);
            do_mtile(SB, oB, oLB, qB, kt == LT);
        }

#pragma unroll
        for (int r = 0; r < 4; r++) {
            const float la = oLA[r], lb = oLB[r];
            const float iar = (la > 0.f) ? 1.f / la : 0.f;
            const float ibr = (lb > 0.f) ? 1.f / lb : 0.f;
            const int qi  = quad * 4 + r;
            const int qrA = qA + qi;
            const int qrB = qB + qi;
#pragma unroll
            for (int dt = 0; dt < 4; dt++) {
                const int col = h * HD_ + dt * 16 + lcol;
                att[(size_t)(b * T_ + qrA) * C_ + col] = f2bf(oA[dt][r] * iar);
                att[(size_t)(b * T_ + qrB) * C_ + col] = f2bf(oB[dt][r] * ibr);
            }
        }
    };

    process_chunk(15 - j, false);   // long chunk first
    process_chunk(j, true);         // complementary: total = 34 tiles/block
}

extern "C" void kernel_launch(void* const* d_in, const int* in_sizes, int n_in,
                              void* d_out, int out_size, void* d_ws, size_t ws_size,
                              hipStream_t stream) {
    char* ws = (char*)d_ws;
    short* qkv     = (short*)(ws);                               // 50331648 B
    short* x_or_at = (short*)(ws + 50331648);                    // 16777216 B (x_bf, then att)
    short* wq_bf   = (short*)(ws + 50331648 + 16777216);         //  6291456 B
    short* wp_bf   = (short*)(ws + 50331648 + 16777216 + 6291456);           // 2097152 B
    short* bias_bf = (short*)(ws + 50331648 + 16777216 + 6291456 + 2097152); //    2048 B
    int*   flag    = (int*)  (ws + 50331648 + 16777216 + 6291456 + 2097152 + 2048);

    const short* x_raw    = (const short*)d_in[0];
    const short* wq_raw   = (const short*)d_in[1];
    const short* wp_raw   = (const short*)d_in[2];
    const short* bias_raw = (const short*)d_in[3];

    // Host-side dtype resolution from in_sizes[0]'s byte signature:
    //   bf16 x = 4*2048*1024*2 = 16777216 B, f32 x = 33554432 B.
    // Any other value (e.g. element counts) -> -1 = device-side detect
    // (the r13-proven flag path), so this is safe under either in_sizes
    // convention.
    int isf32_host = -1;
    if (in_sizes && in_sizes[0] == B_ * T_ * C_ * 2) isf32_host = 0;
    else if (in_sizes && in_sizes[0] == B_ * T_ * C_ * 4) isf32_host = 1;

    dim3 blk(256);

    // convert/detect only when needed: f32 (copies) or ambiguous (detect)
    if (isf32_host != 0) {
        convert_all<<<dim3(6145), blk, 0, stream>>>(
            d_in[0], d_in[1], d_in[2], d_in[3],
            x_or_at, wq_bf, wp_bf, bias_bf, flag);
    }

    // qkv = x @ W_qkv^T   [8192,3072]  -- 128x256 1-barrier, grid 768
    gemm8<false><<<dim3(768), dim3(512), 0, stream>>>(
        x_or_at, x_raw, wq_bf, wq_raw, nullptr, nullptr,
        qkv, B_ * T_, 3 * C_, C_, isf32_host, flag);

    // attention -> att; paired 128-row chunks, 512 blocks (v12, proven)
    attn<<<dim3(B_ * H_ * (T_ / 256)), blk, 0, stream>>>(qkv, x_or_at);

    // out = att @ W_proj^T + b_proj  -- 128x256 1-barrier, grid 256
    gemm8<true><<<dim3(256), dim3(512), 0, stream>>>(
        x_or_at, x_or_at, wp_bf, wp_raw, bias_bf, bias_raw,
        d_out, B_ * T_, C_, C_, isf32_host, flag);
}

// Round 18
// 239.204 us; speedup vs baseline: 1.0614x; 1.0614x over previous
//
#include <hip/hip_runtime.h>
#include <stdint.h>

#define B_ 4
#define T_ 2048
#define C_ 1024
#define H_ 16
#define HD_ 64

typedef __attribute__((ext_vector_type(8))) short short8;
typedef __attribute__((ext_vector_type(4))) float f32x4;

typedef uint32_t __attribute__((address_space(3))) lds_u32;
typedef const uint32_t __attribute__((address_space(1))) glb_u32;

__device__ inline void async16(const void* g, void* l) {
    __builtin_amdgcn_global_load_lds((glb_u32*)g, (lds_u32*)l, 16, 0, 0);
}

__device__ inline short f2bf(float f) {
    union { float f; uint32_t u; } x; x.f = f;
    uint32_t r = (x.u + 0x7fffu + ((x.u >> 16) & 1u)) >> 16;
    return (short)r;
}
__device__ inline float bf2f(short b) {
    union { uint32_t u; float f; } x; x.u = ((uint32_t)(uint16_t)b) << 16;
    return x.f;
}
// v_cvt_pk_bf16_f32: packs two f32 into one u32 of 2x bf16 (RNE). No builtin
// on gfx950 (guide T12 / m240) -> inline asm.
__device__ inline uint32_t cvt_pk_bf16(float lo, float hi) {
    uint32_t r;
    asm("v_cvt_pk_bf16_f32 %0, %1, %2" : "=v"(r) : "v"(lo), "v"(hi));
    return r;
}

#define FENCE asm volatile("" ::: "memory")
#define BAR   do { FENCE; __builtin_amdgcn_s_barrier(); FENCE; } while (0)
#define VMC6  asm volatile("s_waitcnt vmcnt(6)" ::: "memory")

// Dtype detect + canonicalize (r12/r13-proven). r15: only launched when the
// HOST cannot prove bf16 from in_sizes (f32 or ambiguous); bf16-proven runs
// skip this kernel entirely. bf16 device path: flag only, no copies.
__global__ void convert_all(const void* __restrict__ x,  const void* __restrict__ wq,
                            const void* __restrict__ wp, const void* __restrict__ bias,
                            short* __restrict__ xd, short* __restrict__ wqd,
                            short* __restrict__ wpd, short* __restrict__ biasd,
                            int* __restrict__ flag_out)
{
    __shared__ int cnt;
    if (threadIdx.x == 0) cnt = 0;
    __syncthreads();
    int sane = 0;
    const uint32_t* xu = (const uint32_t*)x;
    for (int i = threadIdx.x; i < 1024; i += 256) {
        float v = bf2f((short)(xu[i] & 0xFFFFu));
        float a = fabsf(v);
        if (a > 1e-5f && a < 1e5f) sane++;
    }
    atomicAdd(&cnt, sane);
    __syncthreads();
    const int isf32 = (cnt < 512) ? 1 : 0;

    const int blk = blockIdx.x;
    if (blk == 6144 && threadIdx.x == 0) *flag_out = isf32;
    if (!isf32) return;                      // bf16 inputs: no copies needed

    const void* src; short* dst; int base, n;
    if (blk < 4096)      { src = x;    dst = xd;    base = blk;        n = B_*T_*C_; }
    else if (blk < 5632) { src = wq;   dst = wqd;   base = blk - 4096; n = 3*C_*C_; }
    else if (blk < 6144) { src = wp;   dst = wpd;   base = blk - 5632; n = C_*C_; }
    else                 { src = bias; dst = biasd; base = 0;          n = C_; }
    const int i = (base * 256 + threadIdx.x) * 8;
    if (i >= n) return;
    const float* s = (const float*)src;
    short8 o;
#pragma unroll
    for (int j = 0; j < 8; j++) o[j] = f2bf(s[i + j]);
    *(short8*)&dst[i] = o;
}

// ---------------------------------------------------------------------------
// GEMM v3 (r7/r13 proven): BM=128 x BN=256, BK=64, 8 waves, TRIPLE-buffered
// LDS (144 KB), ONE barrier + ONE counted vmcnt(6) per K-tile. 0 bank
// conflicts, exact grids (768, 256), no epilogue RMW.
// r15: isf32 passed BY VALUE when host-known (isf32_arg in {0,1}); -1 falls
// back to the device flag read (r13-proven path).
// r14 ERRATUM stands: B must stay LDS-staged (direct global B-fragments have
// 2KB lane stride = 16x request amplification; regressed 2.3x).
// ---------------------------------------------------------------------------
template <bool DUAL>
__global__ __launch_bounds__(512, 2) void gemm8(
    const short* __restrict__ Abf,  const short* __restrict__ Araw,
    const short* __restrict__ Bbf,  const short* __restrict__ Braw,
    const short* __restrict__ biasbf, const short* __restrict__ biasraw,
    void* __restrict__ Cout, int M, int N, int K,
    int isf32_arg, const int* __restrict__ flag)
{
    __shared__ short lds[73728];         // 144 KB: A [3][128][64] | B [3][256][64]
    const int isf32 = (isf32_arg >= 0) ? isf32_arg : *flag;
    const short* __restrict__ A  = isf32 ? Abf : Araw;
    const short* __restrict__ Bm = isf32 ? Bbf : Braw;
    const short* bias_bf = DUAL ? (isf32 ? biasbf : biasraw) : (const short*)0;

    const int tid  = threadIdx.x;
    const int lane = tid & 63;
    const int wid  = tid >> 6;
    const int quad = lane >> 4;
    const int lcol = lane & 15;
    const int wm   = wid >> 2;           // 0..1  (64-row slice)
    const int wn   = wid & 3;            // 0..3  (64-col slice)
    const int nbx  = N >> 8;             // N/256

    // XCD swizzle (grid % 8 == 0 for both gemms)
    const int cpx = gridDim.x >> 3;
    const int wg  = (blockIdx.x & 7) * cpx + (blockIdx.x >> 3);
    const int m0 = (wg / nbx) << 7;
    const int n0 = (wg % nbx) << 8;

    // staging: one async16/thread covers 64 rows x 64 cols (8 KB).
    const int srow = tid >> 3;
    const int sch  = ((tid & 7) ^ (srow & 7)) << 3;
    auto stA = [&](int buf, int i, int kt) {   // i in 0..1
        async16(&A[(size_t)(m0 + i * 64 + srow) * K + kt * 64 + sch],
                &lds[buf * 8192 + i * 4096 + tid * 8]);
    };
    auto stB = [&](int buf, int i, int kt) {   // i in 0..3
        async16(&Bm[(size_t)(n0 + i * 64 + srow) * K + kt * 64 + sch],
                &lds[24576 + buf * 16384 + i * 4096 + tid * 8]);
    };
    auto stage6 = [&](int buf, int kt) {
        stB(buf, 0, kt); stB(buf, 1, kt); stB(buf, 2, kt); stB(buf, 3, kt);
        stA(buf, 0, kt); stA(buf, 1, kt);
    };

    f32x4 acc[4][4];
#pragma unroll
    for (int i = 0; i < 4; i++)
#pragma unroll
        for (int j = 0; j < 4; j++) acc[i][j] = f32x4{0.f, 0.f, 0.f, 0.f};

    short8 a[4][2], b[4][2];
    auto rdA2 = [&](int mb, int buf) {
#pragma unroll
        for (int m2 = 0; m2 < 2; m2++)
#pragma unroll
            for (int ks = 0; ks < 2; ks++)
                a[mb + m2][ks] = *(const short8*)&lds[buf * 8192
                    + (wm * 64 + (mb + m2) * 16 + lcol) * 64
                    + ((((ks << 2) | quad) ^ (lcol & 7)) << 3)];
    };
    auto rdB2 = [&](int nb, int buf) {
#pragma unroll
        for (int n2 = 0; n2 < 2; n2++)
#pragma unroll
            for (int ks = 0; ks < 2; ks++)
                b[nb + n2][ks] = *(const short8*)&lds[24576 + buf * 16384
                    + (wn * 64 + (nb + n2) * 16 + lcol) * 64
                    + ((((ks << 2) | quad) ^ (lcol & 7)) << 3)];
    };
    auto mmq = [&](int mb, int nb) {           // one quadrant: 8 MFMA
#pragma unroll
        for (int m2 = 0; m2 < 2; m2++)
#pragma unroll
            for (int n2 = 0; n2 < 2; n2++)
#pragma unroll
                for (int ks = 0; ks < 2; ks++)
                    acc[mb + m2][nb + n2] = __builtin_amdgcn_mfma_f32_16x16x32_bf16(
                        a[mb + m2][ks], b[nb + n2][ks], acc[mb + m2][nb + n2], 0, 0, 0);
    };

    const int NT = K >> 6;                     // 16 K-tiles
    // prologue: tile0 -> buf0, tile1 -> buf1 (12 calls in flight)
    stage6(0, 0);
    stage6(1, 1);

    int bt = 0, b1i = 1, b2i = 2;
    for (int t = 0; t < NT; ++t) {
        const int ts = (t + 2 < NT) ? t + 2 : NT - 1;  // tail stages go to a
        VMC6;                                          // dead buffer (uniform
        BAR;                                           // vmcnt ledger)
        rdA2(0, bt); rdA2(2, bt); rdB2(0, bt); rdB2(2, bt);
        stage6(b2i, ts);
        __builtin_amdgcn_s_setprio(1);
        mmq(0, 0); mmq(2, 0); mmq(0, 2); mmq(2, 2);
        __builtin_amdgcn_s_setprio(0);
        const int nb = bt;                             // rotate buffers
        bt = b1i; b1i = b2i; b2i = nb;
    }

    // epilogue: row-contiguous store order (nf inner) -> per wave per row
    // 128 B written back-to-back; no partial-line RMW.
    float bv[4];
#pragma unroll
    for (int nf = 0; nf < 4; nf++)
        bv[nf] = bias_bf ? bf2f(bias_bf[n0 + wn * 64 + nf * 16 + lcol]) : 0.f;
#pragma unroll
    for (int mf = 0; mf < 4; mf++)
#pragma unroll
        for (int r = 0; r < 4; r++) {
            const int row = m0 + wm * 64 + mf * 16 + quad * 4 + r;
#pragma unroll
            for (int nf = 0; nf < 4; nf++) {
                const int col = n0 + wn * 64 + nf * 16 + lcol;
                const float val = acc[mf][nf][r] + bv[nf];
                const size_t off = (size_t)row * N + col;
                if (DUAL && isf32) ((float*)Cout)[off] = val;
                else               ((short*)Cout)[off] = f2bf(val);
            }
        }
}

// Flash attention v12 VERBATIM (r7/r12/r13/r15/r17 proven, ~64-66 us): two
// causal-complementary 128-row chunks/block (uniform 34 tiles), in-register
// softmax via swapped QK^T + permuted V staging + cvt_pk pack + mask-hoist +
// ones-MFMA l-sum. Sync topology and m-tile structure FROZEN (r8/r9/r11
// restructures all failed verification; r10: occupancy-invariant).
__global__ __launch_bounds__(256) void attn(const short* __restrict__ qkv,
                                            short* __restrict__ att)
{
    __shared__ short lds_k[64][72];      // K  [key][d], pad 64->72 (stride 36 dw)
    __shared__ short lds_vt[64][68];     // V^T [d][key-slot], pad 64->68

    const int tid  = threadIdx.x;
    const int lane = tid & 63;
    const int wave = tid >> 6;
    const int quad = lane >> 4;
    const int lcol = lane & 15;

    const int bh   = blockIdx.x & 63;    // low bits -> XCD pinned per head
    const int j    = blockIdx.x >> 6;    // pair index 0..7
    const int b    = bh >> 4;            // H = 16
    const int h    = bh & 15;

    const size_t rowstride = 3 * C_;     // 3072
    const size_t bhbase = (size_t)b * T_ * rowstride + (size_t)h * (3 * HD_);

    const int kkey = tid >> 2;           // 0..63
    const int kdp  = (tid & 3) * 16;     // 0,16,32,48
    const int vkey = tid & 63;
    const int vkp  = (vkey & 0x23) | ((vkey & 0x0C) << 1) | ((vkey & 0x10) >> 2);
    const int vd0  = (tid >> 6) * 16;    // 0,16,32,48

    short8 vones;
#pragma unroll
    for (int i = 0; i < 8; i++) vones[i] = (short)0x3F80;

    const short* kp; const short* vp;
    short8 kA, kB, vA, vB;
    const size_t TILE_STEP = (size_t)64 * rowstride;
    auto load_init = [&]() {
        kp = &qkv[bhbase + (size_t)kkey * rowstride + HD_ + kdp];
        vp = &qkv[bhbase + (size_t)vkey * rowstride + 2 * HD_ + vd0];
    };
    auto load_tile = [&]() {
        kA = *(const short8*)kp;
        kB = *(const short8*)(kp + 8);
        vA = *(const short8*)vp;
        vB = *(const short8*)(vp + 8);
        kp += TILE_STEP; vp += TILE_STEP;
    };

    const float SC = 0.1803368801f;      // 0.125 * log2(e), folded into Q
    auto scale_frag = [&](short8 q) {
        short8 r;
#pragma unroll
        for (int i = 0; i < 8; i++) r[i] = f2bf(bf2f(q[i]) * SC);
        return r;
    };

    auto process_chunk = [&](int qblk, bool sync_first) {
        const int q0 = qblk * 128;
        const int qA = q0 + wave * 16;          // m-tile A rows
        const int qB = q0 + 64 + wave * 16;     // m-tile B rows

        short8 qfA0, qfA1, qfB0, qfB1;
        {
            const size_t ba = bhbase + (size_t)(qA + lcol) * rowstride + quad * 8;
            qfA0 = scale_frag(*(const short8*)&qkv[ba]);
            qfA1 = scale_frag(*(const short8*)&qkv[ba + 32]);
            const size_t bb = bhbase + (size_t)(qB + lcol) * rowstride + quad * 8;
            qfB0 = scale_frag(*(const short8*)&qkv[bb]);
            qfB1 = scale_frag(*(const short8*)&qkv[bb + 32]);
        }

        f32x4 oA[4], oB[4], oLA, oLB;
#pragma unroll
        for (int i = 0; i < 4; i++) { oA[i] = f32x4{0.f,0.f,0.f,0.f}; oB[i] = f32x4{0.f,0.f,0.f,0.f}; }
        oLA = f32x4{0.f,0.f,0.f,0.f}; oLB = f32x4{0.f,0.f,0.f,0.f};

        load_init();
        load_tile();

        const int LT = 2 * qblk + 1;            // last tile index
        for (int kt = 0; kt <= LT; ++kt) {
            if (kt || sync_first) __syncthreads();  // prior LDS reads done
            *(short8*)&lds_k[kkey][kdp]     = kA;
            *(short8*)&lds_k[kkey][kdp + 8] = kB;
#pragma unroll
            for (int jj = 0; jj < 8; jj++) {
                lds_vt[vd0 + jj][vkp]     = vA[jj];
                lds_vt[vd0 + 8 + jj][vkp] = vB[jj];
            }
            __syncthreads();
            if (kt < LT) load_tile();            // prefetch overlaps compute

            const int k0 = kt * 64;
            const bool doA = (kt < LT);      // A's range is tiles 0..LT-1

            f32x4 SA[4], SB[4];
#pragma unroll
            for (int t = 0; t < 4; t++) {
                const short8 kf0 = *(const short8*)&lds_k[t * 16 + lcol][quad * 8];
                const short8 kf1 = *(const short8*)&lds_k[t * 16 + lcol][32 + quad * 8];
                SB[t] = f32x4{0.f, 0.f, 0.f, 0.f};
                SB[t] = __builtin_amdgcn_mfma_f32_16x16x32_bf16(kf0, qfB0, SB[t], 0, 0, 0);
                SB[t] = __builtin_amdgcn_mfma_f32_16x16x32_bf16(kf1, qfB1, SB[t], 0, 0, 0);
                if (doA) {
                    SA[t] = f32x4{0.f, 0.f, 0.f, 0.f};
                    SA[t] = __builtin_amdgcn_mfma_f32_16x16x32_bf16(kf0, qfA0, SA[t], 0, 0, 0);
                    SA[t] = __builtin_amdgcn_mfma_f32_16x16x32_bf16(kf1, qfA1, SA[t], 0, 0, 0);
                }
            }

            short8 vf[4][2];
#pragma unroll
            for (int dt = 0; dt < 4; dt++) {
                vf[dt][0] = *(const short8*)&lds_vt[dt * 16 + lcol][quad * 8];
                vf[dt][1] = *(const short8*)&lds_vt[dt * 16 + lcol][32 + quad * 8];
            }

            auto do_mtile = [&](f32x4 (&S)[4], f32x4 (&o)[4], f32x4& oL,
                                int qX, bool maskT) {
                if (maskT) {
                    const int qthr = qX + lcol - k0 - quad * 4;  // per-lane
#pragma unroll
                    for (int t = 0; t < 4; t++)
#pragma unroll
                        for (int r = 0; r < 4; r++) {
                            float e = __builtin_amdgcn_exp2f(S[t][r]);
                            if (t * 16 + r > qthr) e = 0.f;
                            S[t][r] = e;
                        }
                } else {
#pragma unroll
                    for (int t = 0; t < 4; t++)
#pragma unroll
                        for (int r = 0; r < 4; r++)
                            S[t][r] = __builtin_amdgcn_exp2f(S[t][r]);
                }
                union { uint32_t u[4]; short8 s; } p0, p1;
#pragma unroll
                for (int w = 0; w < 4; w++) {
                    const int t0 = w >> 1, r0 = (w & 1) * 2;
                    p0.u[w] = cvt_pk_bf16(S[t0][r0],     S[t0][r0 + 1]);
                    p1.u[w] = cvt_pk_bf16(S[2 + t0][r0], S[2 + t0][r0 + 1]);
                }
                oL = __builtin_amdgcn_mfma_f32_16x16x32_bf16(p0.s, vones, oL, 0, 0, 0);
                oL = __builtin_amdgcn_mfma_f32_16x16x32_bf16(p1.s, vones, oL, 0, 0, 0);
#pragma unroll
                for (int dt = 0; dt < 4; dt++) {
                    o[dt] = __builtin_amdgcn_mfma_f32_16x16x32_bf16(p0.s, vf[dt][0], o[dt], 0, 0, 0);
                    o[dt] = __builtin_amdgcn_mfma_f32_16x16x32_bf16(p1.s, vf[dt][1], o[dt], 0, 0, 0);
                }
            };

            if (doA) do_mtile(SA, oA, oLA, qA, kt == LT - 1);
            do_mtile(SB, oB, oLB, qB, kt == LT);
        }

#pragma unroll
        for (int r = 0; r < 4; r++) {
            const float la = oLA[r], lb = oLB[r];
            const float iar = (la > 0.f) ? 1.f / la : 0.f;
            const float ibr = (lb > 0.f) ? 1.f / lb : 0.f;
            const int qi  = quad * 4 + r;
            const int qrA = qA + qi;
            const int qrB = qB + qi;
#pragma unroll
            for (int dt = 0; dt < 4; dt++) {
                const int col = h * HD_ + dt * 16 + lcol;
                att[(size_t)(b * T_ + qrA) * C_ + col] = f2bf(oA[dt][r] * iar);
                att[(size_t)(b * T_ + qrB) * C_ + col] = f2bf(oB[dt][r] * ibr);
            }
        }
    };

    process_chunk(15 - j, false);   // long chunk first
    process_chunk(j, true);         // complementary: total = 34 tiles/block
}

extern "C" void kernel_launch(void* const* d_in, const int* in_sizes, int n_in,
                              void* d_out, int out_size, void* d_ws, size_t ws_size,
                              hipStream_t stream) {
    char* ws = (char*)d_ws;
    short* qkv     = (short*)(ws);                               // 50331648 B
    short* x_or_at = (short*)(ws + 50331648);                    // 16777216 B (x_bf, then att)
    short* wq_bf   = (short*)(ws + 50331648 + 16777216);         //  6291456 B
    short* wp_bf   = (short*)(ws + 50331648 + 16777216 + 6291456);           // 2097152 B
    short* bias_bf = (short*)(ws + 50331648 + 16777216 + 6291456 + 2097152); //    2048 B
    int*   flag    = (int*)  (ws + 50331648 + 16777216 + 6291456 + 2097152 + 2048);

    const short* x_raw    = (const short*)d_in[0];
    const short* wq_raw   = (const short*)d_in[1];
    const short* wp_raw   = (const short*)d_in[2];
    const short* bias_raw = (const short*)d_in[3];

    // Host-side dtype resolution from in_sizes[0]'s byte signature:
    //   bf16 x = 4*2048*1024*2 = 16777216 B, f32 x = 33554432 B.
    // Any other value (e.g. element counts) -> -1 = device-side detect
    // (the r13-proven flag path), so this is safe under either in_sizes
    // convention.
    int isf32_host = -1;
    if (in_sizes && in_sizes[0] == B_ * T_ * C_ * 2) isf32_host = 0;
    else if (in_sizes && in_sizes[0] == B_ * T_ * C_ * 4) isf32_host = 1;

    dim3 blk(256);

    // convert/detect only when needed: f32 (copies) or ambiguous (detect)
    if (isf32_host != 0) {
        convert_all<<<dim3(6145), blk, 0, stream>>>(
            d_in[0], d_in[1], d_in[2], d_in[3],
            x_or_at, wq_bf, wp_bf, bias_bf, flag);
    }

    // qkv = x @ W_qkv^T   [8192,3072]  -- 128x256 1-barrier, grid 768
    gemm8<false><<<dim3(768), dim3(512), 0, stream>>>(
        x_or_at, x_raw, wq_bf, wq_raw, nullptr, nullptr,
        qkv, B_ * T_, 3 * C_, C_, isf32_host, flag);

    // attention -> att; paired 128-row chunks, 512 blocks (v12, proven)
    attn<<<dim3(B_ * H_ * (T_ / 256)), blk, 0, stream>>>(qkv, x_or_at);

    // out = att @ W_proj^T + b_proj  -- 128x256 1-barrier, grid 256
    gemm8<true><<<dim3(256), dim3(512), 0, stream>>>(
        x_or_at, x_or_at, wp_bf, wp_raw, bias_bf, bias_raw,
        d_out, B_ * T_, C_, C_, isf32_host, flag);
}

// Round 19
// 227.235 us; speedup vs baseline: 1.1173x; 1.0527x over previous
//
#include <hip/hip_runtime.h>
#include <stdint.h>

#define B_ 4
#define T_ 2048
#define C_ 1024
#define H_ 16
#define HD_ 64

typedef __attribute__((ext_vector_type(8))) short short8;
typedef __attribute__((ext_vector_type(4))) float f32x4;

typedef uint32_t __attribute__((address_space(3))) lds_u32;
typedef const uint32_t __attribute__((address_space(1))) glb_u32;

__device__ inline void async16(const void* g, void* l) {
    __builtin_amdgcn_global_load_lds((glb_u32*)g, (lds_u32*)l, 16, 0, 0);
}

__device__ inline short f2bf(float f) {
    union { float f; uint32_t u; } x; x.f = f;
    uint32_t r = (x.u + 0x7fffu + ((x.u >> 16) & 1u)) >> 16;
    return (short)r;
}
__device__ inline float bf2f(short b) {
    union { uint32_t u; float f; } x; x.u = ((uint32_t)(uint16_t)b) << 16;
    return x.f;
}
// v_cvt_pk_bf16_f32: packs two f32 into one u32 of 2x bf16 (RNE). No builtin
// on gfx950 (guide T12 / m240) -> inline asm.
__device__ inline uint32_t cvt_pk_bf16(float lo, float hi) {
    uint32_t r;
    asm("v_cvt_pk_bf16_f32 %0, %1, %2" : "=v"(r) : "v"(lo), "v"(hi));
    return r;
}

#define FENCE asm volatile("" ::: "memory")
#define BAR   do { FENCE; __builtin_amdgcn_s_barrier(); FENCE; } while (0)
#define VMC6  asm volatile("s_waitcnt vmcnt(6)" ::: "memory")

// Dtype detect + canonicalize (r12/r13-proven). r15: only launched when the
// HOST cannot prove bf16 from in_sizes (f32 or ambiguous); bf16-proven runs
// skip this kernel entirely. bf16 device path: flag only, no copies.
__global__ void convert_all(const void* __restrict__ x,  const void* __restrict__ wq,
                            const void* __restrict__ wp, const void* __restrict__ bias,
                            short* __restrict__ xd, short* __restrict__ wqd,
                            short* __restrict__ wpd, short* __restrict__ biasd,
                            int* __restrict__ flag_out)
{
    __shared__ int cnt;
    if (threadIdx.x == 0) cnt = 0;
    __syncthreads();
    int sane = 0;
    const uint32_t* xu = (const uint32_t*)x;
    for (int i = threadIdx.x; i < 1024; i += 256) {
        float v = bf2f((short)(xu[i] & 0xFFFFu));
        float a = fabsf(v);
        if (a > 1e-5f && a < 1e5f) sane++;
    }
    atomicAdd(&cnt, sane);
    __syncthreads();
    const int isf32 = (cnt < 512) ? 1 : 0;

    const int blk = blockIdx.x;
    if (blk == 6144 && threadIdx.x == 0) *flag_out = isf32;
    if (!isf32) return;                      // bf16 inputs: no copies needed

    const void* src; short* dst; int base, n;
    if (blk < 4096)      { src = x;    dst = xd;    base = blk;        n = B_*T_*C_; }
    else if (blk < 5632) { src = wq;   dst = wqd;   base = blk - 4096; n = 3*C_*C_; }
    else if (blk < 6144) { src = wp;   dst = wpd;   base = blk - 5632; n = C_*C_; }
    else                 { src = bias; dst = biasd; base = 0;          n = C_; }
    const int i = (base * 256 + threadIdx.x) * 8;
    if (i >= n) return;
    const float* s = (const float*)src;
    short8 o;
#pragma unroll
    for (int j = 0; j < 8; j++) o[j] = f2bf(s[i + j]);
    *(short8*)&dst[i] = o;
}

// ---------------------------------------------------------------------------
// GEMM v3 (r7/r13 proven): BM=128 x BN=256, BK=64, 8 waves, TRIPLE-buffered
// LDS (144 KB), ONE barrier + ONE counted vmcnt(6) per K-tile. 0 bank
// conflicts, exact grids (768, 256), no epilogue RMW.
// r15: isf32 passed BY VALUE when host-known (isf32_arg in {0,1}); -1 falls
// back to the device flag read (r13-proven path).
// r14 ERRATUM stands: B must stay LDS-staged (direct global B-fragments have
// 2KB lane stride = 16x request amplification; regressed 2.3x).
// ---------------------------------------------------------------------------
template <bool DUAL>
__global__ __launch_bounds__(512, 2) void gemm8(
    const short* __restrict__ Abf,  const short* __restrict__ Araw,
    const short* __restrict__ Bbf,  const short* __restrict__ Braw,
    const short* __restrict__ biasbf, const short* __restrict__ biasraw,
    void* __restrict__ Cout, int M, int N, int K,
    int isf32_arg, const int* __restrict__ flag)
{
    __shared__ short lds[73728];         // 144 KB: A [3][128][64] | B [3][256][64]
    const int isf32 = (isf32_arg >= 0) ? isf32_arg : *flag;
    const short* __restrict__ A  = isf32 ? Abf : Araw;
    const short* __restrict__ Bm = isf32 ? Bbf : Braw;
    const short* bias_bf = DUAL ? (isf32 ? biasbf : biasraw) : (const short*)0;

    const int tid  = threadIdx.x;
    const int lane = tid & 63;
    const int wid  = tid >> 6;
    const int quad = lane >> 4;
    const int lcol = lane & 15;
    const int wm   = wid >> 2;           // 0..1  (64-row slice)
    const int wn   = wid & 3;            // 0..3  (64-col slice)
    const int nbx  = N >> 8;             // N/256

    // XCD swizzle (grid % 8 == 0 for both gemms)
    const int cpx = gridDim.x >> 3;
    const int wg  = (blockIdx.x & 7) * cpx + (blockIdx.x >> 3);
    const int m0 = (wg / nbx) << 7;
    const int n0 = (wg % nbx) << 8;

    // staging: one async16/thread covers 64 rows x 64 cols (8 KB).
    const int srow = tid >> 3;
    const int sch  = ((tid & 7) ^ (srow & 7)) << 3;
    auto stA = [&](int buf, int i, int kt) {   // i in 0..1
        async16(&A[(size_t)(m0 + i * 64 + srow) * K + kt * 64 + sch],
                &lds[buf * 8192 + i * 4096 + tid * 8]);
    };
    auto stB = [&](int buf, int i, int kt) {   // i in 0..3
        async16(&Bm[(size_t)(n0 + i * 64 + srow) * K + kt * 64 + sch],
                &lds[24576 + buf * 16384 + i * 4096 + tid * 8]);
    };
    auto stage6 = [&](int buf, int kt) {
        stB(buf, 0, kt); stB(buf, 1, kt); stB(buf, 2, kt); stB(buf, 3, kt);
        stA(buf, 0, kt); stA(buf, 1, kt);
    };

    f32x4 acc[4][4];
#pragma unroll
    for (int i = 0; i < 4; i++)
#pragma unroll
        for (int j = 0; j < 4; j++) acc[i][j] = f32x4{0.f, 0.f, 0.f, 0.f};

    short8 a[4][2], b[4][2];
    auto rdA2 = [&](int mb, int buf) {
#pragma unroll
        for (int m2 = 0; m2 < 2; m2++)
#pragma unroll
            for (int ks = 0; ks < 2; ks++)
                a[mb + m2][ks] = *(const short8*)&lds[buf * 8192
                    + (wm * 64 + (mb + m2) * 16 + lcol) * 64
                    + ((((ks << 2) | quad) ^ (lcol & 7)) << 3)];
    };
    auto rdB2 = [&](int nb, int buf) {
#pragma unroll
        for (int n2 = 0; n2 < 2; n2++)
#pragma unroll
            for (int ks = 0; ks < 2; ks++)
                b[nb + n2][ks] = *(const short8*)&lds[24576 + buf * 16384
                    + (wn * 64 + (nb + n2) * 16 + lcol) * 64
                    + ((((ks << 2) | quad) ^ (lcol & 7)) << 3)];
    };
    auto mmq = [&](int mb, int nb) {           // one quadrant: 8 MFMA
#pragma unroll
        for (int m2 = 0; m2 < 2; m2++)
#pragma unroll
            for (int n2 = 0; n2 < 2; n2++)
#pragma unroll
                for (int ks = 0; ks < 2; ks++)
                    acc[mb + m2][nb + n2] = __builtin_amdgcn_mfma_f32_16x16x32_bf16(
                        a[mb + m2][ks], b[nb + n2][ks], acc[mb + m2][nb + n2], 0, 0, 0);
    };

    const int NT = K >> 6;                     // 16 K-tiles
    // prologue: tile0 -> buf0, tile1 -> buf1 (12 calls in flight)
    stage6(0, 0);
    stage6(1, 1);

    int bt = 0, b1i = 1, b2i = 2;
    for (int t = 0; t < NT; ++t) {
        const int ts = (t + 2 < NT) ? t + 2 : NT - 1;  // tail stages go to a
        VMC6;                                          // dead buffer (uniform
        BAR;                                           // vmcnt ledger)
        rdA2(0, bt); rdA2(2, bt); rdB2(0, bt); rdB2(2, bt);
        stage6(b2i, ts);
        __builtin_amdgcn_s_setprio(1);
        mmq(0, 0); mmq(2, 0); mmq(0, 2); mmq(2, 2);
        __builtin_amdgcn_s_setprio(0);
        const int nb = bt;                             // rotate buffers
        bt = b1i; b1i = b2i; b2i = nb;
    }

    // epilogue: row-contiguous store order (nf inner) -> per wave per row
    // 128 B written back-to-back; no partial-line RMW.
    float bv[4];
#pragma unroll
    for (int nf = 0; nf < 4; nf++)
        bv[nf] = bias_bf ? bf2f(bias_bf[n0 + wn * 64 + nf * 16 + lcol]) : 0.f;
#pragma unroll
    for (int mf = 0; mf < 4; mf++)
#pragma unroll
        for (int r = 0; r < 4; r++) {
            const int row = m0 + wm * 64 + mf * 16 + quad * 4 + r;
#pragma unroll
            for (int nf = 0; nf < 4; nf++) {
                const int col = n0 + wn * 64 + nf * 16 + lcol;
                const float val = acc[mf][nf][r] + bv[nf];
                const size_t off = (size_t)row * N + col;
                if (DUAL && isf32) ((float*)Cout)[off] = val;
                else               ((short*)Cout)[off] = f2bf(val);
            }
        }
}

// Flash attention v12 VERBATIM (proven passing r7/r12/r13/r15/r17/r18,
// 64-77 us clock-dependent): two causal-complementary 128-row chunks/block
// (uniform 34 tiles), in-register softmax via swapped QK^T + permuted V
// staging + cvt_pk pack + mask-hoist + ones-MFMA l-sum. Sync topology and
// m-tile structure FROZEN (r8/r9/r11 restructures all failed verification;
// r10: occupancy-invariant).
__global__ __launch_bounds__(256) void attn(const short* __restrict__ qkv,
                                            short* __restrict__ att)
{
    __shared__ short lds_k[64][72];      // K  [key][d], pad 64->72 (stride 36 dw)
    __shared__ short lds_vt[64][68];     // V^T [d][key-slot], pad 64->68

    const int tid  = threadIdx.x;
    const int lane = tid & 63;
    const int wave = tid >> 6;
    const int quad = lane >> 4;
    const int lcol = lane & 15;

    const int bh   = blockIdx.x & 63;    // low bits -> XCD pinned per head
    const int j    = blockIdx.x >> 6;    // pair index 0..7
    const int b    = bh >> 4;            // H = 16
    const int h    = bh & 15;

    const size_t rowstride = 3 * C_;     // 3072
    const size_t bhbase = (size_t)b * T_ * rowstride + (size_t)h * (3 * HD_);

    const int kkey = tid >> 2;           // 0..63
    const int kdp  = (tid & 3) * 16;     // 0,16,32,48
    const int vkey = tid & 63;
    const int vkp  = (vkey & 0x23) | ((vkey & 0x0C) << 1) | ((vkey & 0x10) >> 2);
    const int vd0  = (tid >> 6) * 16;    // 0,16,32,48

    short8 vones;
#pragma unroll
    for (int i = 0; i < 8; i++) vones[i] = (short)0x3F80;

    const short* kp; const short* vp;
    short8 kA, kB, vA, vB;
    const size_t TILE_STEP = (size_t)64 * rowstride;
    auto load_init = [&]() {
        kp = &qkv[bhbase + (size_t)kkey * rowstride + HD_ + kdp];
        vp = &qkv[bhbase + (size_t)vkey * rowstride + 2 * HD_ + vd0];
    };
    auto load_tile = [&]() {
        kA = *(const short8*)kp;
        kB = *(const short8*)(kp + 8);
        vA = *(const short8*)vp;
        vB = *(const short8*)(vp + 8);
        kp += TILE_STEP; vp += TILE_STEP;
    };

    const float SC = 0.1803368801f;      // 0.125 * log2(e), folded into Q
    auto scale_frag = [&](short8 q) {
        short8 r;
#pragma unroll
        for (int i = 0; i < 8; i++) r[i] = f2bf(bf2f(q[i]) * SC);
        return r;
    };

    auto process_chunk = [&](int qblk, bool sync_first) {
        const int q0 = qblk * 128;
        const int qA = q0 + wave * 16;          // m-tile A rows
        const int qB = q0 + 64 + wave * 16;     // m-tile B rows

        short8 qfA0, qfA1, qfB0, qfB1;
        {
            const size_t ba = bhbase + (size_t)(qA + lcol) * rowstride + quad * 8;
            qfA0 = scale_frag(*(const short8*)&qkv[ba]);
            qfA1 = scale_frag(*(const short8*)&qkv[ba + 32]);
            const size_t bb = bhbase + (size_t)(qB + lcol) * rowstride + quad * 8;
            qfB0 = scale_frag(*(const short8*)&qkv[bb]);
            qfB1 = scale_frag(*(const short8*)&qkv[bb + 32]);
        }

        f32x4 oA[4], oB[4], oLA, oLB;
#pragma unroll
        for (int i = 0; i < 4; i++) { oA[i] = f32x4{0.f,0.f,0.f,0.f}; oB[i] = f32x4{0.f,0.f,0.f,0.f}; }
        oLA = f32x4{0.f,0.f,0.f,0.f}; oLB = f32x4{0.f,0.f,0.f,0.f};

        load_init();
        load_tile();

        const int LT = 2 * qblk + 1;            // last tile index
        for (int kt = 0; kt <= LT; ++kt) {
            if (kt || sync_first) __syncthreads();  // prior LDS reads done
            *(short8*)&lds_k[kkey][kdp]     = kA;
            *(short8*)&lds_k[kkey][kdp + 8] = kB;
#pragma unroll
            for (int jj = 0; jj < 8; jj++) {
                lds_vt[vd0 + jj][vkp]     = vA[jj];
                lds_vt[vd0 + 8 + jj][vkp] = vB[jj];
            }
            __syncthreads();
            if (kt < LT) load_tile();            // prefetch overlaps compute

            const int k0 = kt * 64;
            const bool doA = (kt < LT);      // A's range is tiles 0..LT-1

            f32x4 SA[4], SB[4];
#pragma unroll
            for (int t = 0; t < 4; t++) {
                const short8 kf0 = *(const short8*)&lds_k[t * 16 + lcol][quad * 8];
                const short8 kf1 = *(const short8*)&lds_k[t * 16 + lcol][32 + quad * 8];
                SB[t] = f32x4{0.f, 0.f, 0.f, 0.f};
                SB[t] = __builtin_amdgcn_mfma_f32_16x16x32_bf16(kf0, qfB0, SB[t], 0, 0, 0);
                SB[t] = __builtin_amdgcn_mfma_f32_16x16x32_bf16(kf1, qfB1, SB[t], 0, 0, 0);
                if (doA) {
                    SA[t] = f32x4{0.f, 0.f, 0.f, 0.f};
                    SA[t] = __builtin_amdgcn_mfma_f32_16x16x32_bf16(kf0, qfA0, SA[t], 0, 0, 0);
                    SA[t] = __builtin_amdgcn_mfma_f32_16x16x32_bf16(kf1, qfA1, SA[t], 0, 0, 0);
                }
            }

            short8 vf[4][2];
#pragma unroll
            for (int dt = 0; dt < 4; dt++) {
                vf[dt][0] = *(const short8*)&lds_vt[dt * 16 + lcol][quad * 8];
                vf[dt][1] = *(const short8*)&lds_vt[dt * 16 + lcol][32 + quad * 8];
            }

            auto do_mtile = [&](f32x4 (&S)[4], f32x4 (&o)[4], f32x4& oL,
                                int qX, bool maskT) {
                if (maskT) {
                    const int qthr = qX + lcol - k0 - quad * 4;  // per-lane
#pragma unroll
                    for (int t = 0; t < 4; t++)
#pragma unroll
                        for (int r = 0; r < 4; r++) {
                            float e = __builtin_amdgcn_exp2f(S[t][r]);
                            if (t * 16 + r > qthr) e = 0.f;
                            S[t][r] = e;
                        }
                } else {
#pragma unroll
                    for (int t = 0; t < 4; t++)
#pragma unroll
                        for (int r = 0; r < 4; r++)
                            S[t][r] = __builtin_amdgcn_exp2f(S[t][r]);
                }
                union { uint32_t u[4]; short8 s; } p0, p1;
#pragma unroll
                for (int w = 0; w < 4; w++) {
                    const int t0 = w >> 1, r0 = (w & 1) * 2;
                    p0.u[w] = cvt_pk_bf16(S[t0][r0],     S[t0][r0 + 1]);
                    p1.u[w] = cvt_pk_bf16(S[2 + t0][r0], S[2 + t0][r0 + 1]);
                }
                oL = __builtin_amdgcn_mfma_f32_16x16x32_bf16(p0.s, vones, oL, 0, 0, 0);
                oL = __builtin_amdgcn_mfma_f32_16x16x32_bf16(p1.s, vones, oL, 0, 0, 0);
#pragma unroll
                for (int dt = 0; dt < 4; dt++) {
                    o[dt] = __builtin_amdgcn_mfma_f32_16x16x32_bf16(p0.s, vf[dt][0], o[dt], 0, 0, 0);
                    o[dt] = __builtin_amdgcn_mfma_f32_16x16x32_bf16(p1.s, vf[dt][1], o[dt], 0, 0, 0);
                }
            };

            if (doA) do_mtile(SA, oA, oLA, qA, kt == LT - 1);
            do_mtile(SB, oB, oLB, qB, kt == LT);
        }

#pragma unroll
        for (int r = 0; r < 4; r++) {
            const float la = oLA[r], lb = oLB[r];
            const float iar = (la > 0.f) ? 1.f / la : 0.f;
            const float ibr = (lb > 0.f) ? 1.f / lb : 0.f;
            const int qi  = quad * 4 + r;
            const int qrA = qA + qi;
            const int qrB = qB + qi;
#pragma unroll
            for (int dt = 0; dt < 4; dt++) {
                const int col = h * HD_ + dt * 16 + lcol;
                att[(size_t)(b * T_ + qrA) * C_ + col] = f2bf(oA[dt][r] * iar);
                att[(size_t)(b * T_ + qrB) * C_ + col] = f2bf(oB[dt][r] * ibr);
            }
        }
    };

    process_chunk(15 - j, false);   // long chunk first
    process_chunk(j, true);         // complementary: total = 34 tiles/block
}

extern "C" void kernel_launch(void* const* d_in, const int* in_sizes, int n_in,
                              void* d_out, int out_size, void* d_ws, size_t ws_size,
                              hipStream_t stream) {
    char* ws = (char*)d_ws;
    short* qkv     = (short*)(ws);                               // 50331648 B
    short* x_or_at = (short*)(ws + 50331648);                    // 16777216 B (x_bf, then att)
    short* wq_bf   = (short*)(ws + 50331648 + 16777216);         //  6291456 B
    short* wp_bf   = (short*)(ws + 50331648 + 16777216 + 6291456);           // 2097152 B
    short* bias_bf = (short*)(ws + 50331648 + 16777216 + 6291456 + 2097152); //    2048 B
    int*   flag    = (int*)  (ws + 50331648 + 16777216 + 6291456 + 2097152 + 2048);

    const short* x_raw    = (const short*)d_in[0];
    const short* wq_raw   = (const short*)d_in[1];
    const short* wp_raw   = (const short*)d_in[2];
    const short* bias_raw = (const short*)d_in[3];

    // Host-side dtype resolution from in_sizes[0]'s byte signature:
    //   bf16 x = 4*2048*1024*2 = 16777216 B, f32 x = 33554432 B.
    // Any other value (e.g. element counts) -> -1 = device-side detect
    // (the r13-proven flag path), so this is safe under either in_sizes
    // convention.
    int isf32_host = -1;
    if (in_sizes && in_sizes[0] == B_ * T_ * C_ * 2) isf32_host = 0;
    else if (in_sizes && in_sizes[0] == B_ * T_ * C_ * 4) isf32_host = 1;

    dim3 blk(256);

    // convert/detect only when needed: f32 (copies) or ambiguous (detect)
    if (isf32_host != 0) {
        convert_all<<<dim3(6145), blk, 0, stream>>>(
            d_in[0], d_in[1], d_in[2], d_in[3],
            x_or_at, wq_bf, wp_bf, bias_bf, flag);
    }

    // qkv = x @ W_qkv^T   [8192,3072]  -- 128x256 1-barrier, grid 768
    gemm8<false><<<dim3(768), dim3(512), 0, stream>>>(
        x_or_at, x_raw, wq_bf, wq_raw, nullptr, nullptr,
        qkv, B_ * T_, 3 * C_, C_, isf32_host, flag);

    // attention -> att; paired 128-row chunks, 512 blocks (v12, proven)
    attn<<<dim3(B_ * H_ * (T_ / 256)), blk, 0, stream>>>(qkv, x_or_at);

    // out = att @ W_proj^T + b_proj  -- 128x256 1-barrier, grid 256
    gemm8<true><<<dim3(256), dim3(512), 0, stream>>>(
        x_or_at, x_or_at, wp_bf, wp_raw, bias_bf, bias_raw,
        d_out, B_ * T_, C_, C_, isf32_host, flag);
}